// Round 1
// baseline (4168.889 us; speedup 1.0000x reference)
//
#include <hip/hip_runtime.h>
#include <math.h>

#define VOCAB  50257
#define EMBED  256
#define NHEAD  8
#define HEAD   32
#define TLEN   512
#define BATCH  4
#define ROWS   (BATCH*TLEN)     /* 2048 */
#define HIDDEN 1024
#define LOGN   ((size_t)ROWS * (size_t)VOCAB)
#define SCALE  0.0625f          /* EMBED^-0.5 = 1/16 */

/* ---------------- K1: x = tok_emb[idx] + pos_emb[t] ---------------- */
__global__ void k_embed(const int* __restrict__ idx, const float* __restrict__ tok,
                        const float* __restrict__ pos, float* __restrict__ x) {
    int r = blockIdx.x, e = threadIdx.x;
    x[r*EMBED + e] = tok[(size_t)idx[r]*EMBED + e] + pos[(r & (TLEN-1))*EMBED + e];
}

/* ---------------- K2: q/k/v[n][r][h] = x[r,:] @ W[n,:,h] ------------ */
__global__ void k_qkv(const float* __restrict__ x,  const float* __restrict__ Wq,
                      const float* __restrict__ Wk, const float* __restrict__ Wv,
                      float* __restrict__ q, float* __restrict__ k, float* __restrict__ v) {
    __shared__ float xs[EMBED];
    int r = blockIdx.x, tid = threadIdx.x;
    xs[tid] = x[r*EMBED + tid];
    __syncthreads();
    int n = tid >> 5, h = tid & 31;
    const float* wq = Wq + n*EMBED*HEAD + h;
    const float* wk = Wk + n*EMBED*HEAD + h;
    const float* wv = Wv + n*EMBED*HEAD + h;
    float aq = 0.f, ak = 0.f, av = 0.f;
    for (int e = 0; e < EMBED; e++) {
        float xv = xs[e];
        aq += xv * wq[e*HEAD];
        ak += xv * wk[e*HEAD];
        av += xv * wv[e*HEAD];
    }
    int o = (n*ROWS + r)*HEAD + h;
    q[o] = aq; k[o] = ak; v[o] = av;
}

/* ------- K3a: per (n,b) column stats of softmax over QUERY axis -------
   For column s: M[s] = max_{t>=s} score(t,s), RL[s] = 1/sum exp(.-M).
   qs stored [h][t] so per-lane t-varying reads are bank-conflict-free.  */
__global__ void k_colstats(const float* __restrict__ q, const float* __restrict__ k,
                           float* __restrict__ colM, float* __restrict__ colRL) {
    __shared__ float qs[HEAD][TLEN];           /* 64 KB */
    int nb = blockIdx.x;                       /* nb = n*4 + b */
    const float* qb = q + nb*TLEN*HEAD;
    const float* kb = k + nb*TLEN*HEAD;
    for (int i = threadIdx.x; i < TLEN*HEAD; i += 512)
        qs[i & 31][i >> 5] = qb[i];
    __syncthreads();
    int s = threadIdx.x;                       /* 512 threads: one column each */
    float kreg[HEAD];
#pragma unroll
    for (int h = 0; h < HEAD; h++) kreg[h] = kb[s*HEAD + h];
    float m = -1e30f, l = 0.f;
    for (int t = s; t < TLEN; t++) {
        float sc = 0.f;
#pragma unroll
        for (int h = 0; h < HEAD; h++) sc += qs[h][t] * kreg[h];
        sc *= SCALE;
        float nm = fmaxf(m, sc);
        l = l * __expf(m - nm) + __expf(sc - nm);
        m = nm;
    }
    colM[nb*TLEN + s]  = m;
    colRL[nb*TLEN + s] = 1.0f / l;
}

/* ------- K3b: out[t,:] = sum_{s<=t} exp(sc(t,s)-M[s])*RL[s] * v[s,:] ---
   k/v staged in 256-column chunks (64 KB LDS).                          */
__global__ void k_attnout(const float* __restrict__ q, const float* __restrict__ k,
                          const float* __restrict__ v, const float* __restrict__ colM,
                          const float* __restrict__ colRL, float* __restrict__ outc) {
    __shared__ float ks[256][HEAD];            /* 32 KB */
    __shared__ float vs[256][HEAD];            /* 32 KB */
    int nb = blockIdx.x;
    int n = nb >> 2, b = nb & 3;
    int base = nb*TLEN*HEAD;
    int t = threadIdx.x;
    int nbT = nb*TLEN;
    float qr[HEAD], acc[HEAD];
#pragma unroll
    for (int h = 0; h < HEAD; h++) { qr[h] = q[base + t*HEAD + h]; acc[h] = 0.f; }
    for (int c0 = 0; c0 < TLEN; c0 += 256) {
        __syncthreads();
        for (int i = threadIdx.x; i < 256*HEAD; i += 512) {
            ks[i >> 5][i & 31] = k[base + c0*HEAD + i];
            vs[i >> 5][i & 31] = v[base + c0*HEAD + i];
        }
        __syncthreads();
        int send = t < c0 + 255 ? t : c0 + 255;
        for (int s = c0; s <= send; s++) {
            float sc = 0.f;
#pragma unroll
            for (int h = 0; h < HEAD; h++) sc += qr[h] * ks[s - c0][h];
            float w = __expf(sc * SCALE - colM[nbT + s]) * colRL[nbT + s];
#pragma unroll
            for (int h = 0; h < HEAD; h++) acc[h] += w * vs[s - c0][h];
        }
    }
    int r = b*TLEN + t;
#pragma unroll
    for (int h = 0; h < HEAD; h++) outc[r*EMBED + n*HEAD + h] = acc[h];
}

/* ---------------- K4: h = relu(outc @ W1 + b1), 8 rows/block ---------- */
__global__ void k_mlp(const float* __restrict__ outc, const float* __restrict__ W1,
                      const float* __restrict__ b1, float* __restrict__ hbuf) {
    __shared__ float xs[8][EMBED];             /* 8 KB */
    int r0 = blockIdx.x * 8, tid = threadIdx.x;
    for (int i = tid; i < 8*EMBED; i += 256) xs[i >> 8][i & 255] = outc[r0*EMBED + i];
    __syncthreads();
    int j0 = tid * 4;
    float acc[8][4];
#pragma unroll
    for (int i = 0; i < 8; i++)
#pragma unroll
        for (int c = 0; c < 4; c++) acc[i][c] = 0.f;
    for (int e = 0; e < EMBED; e++) {
        float4 w = *(const float4*)(W1 + e*HIDDEN + j0);
#pragma unroll
        for (int i = 0; i < 8; i++) {
            float xv = xs[i][e];
            acc[i][0] += xv * w.x; acc[i][1] += xv * w.y;
            acc[i][2] += xv * w.z; acc[i][3] += xv * w.w;
        }
    }
    float4 bb = *(const float4*)(b1 + j0);
#pragma unroll
    for (int i = 0; i < 8; i++) {
        float4 o;
        o.x = fmaxf(acc[i][0] + bb.x, 0.f);
        o.y = fmaxf(acc[i][1] + bb.y, 0.f);
        o.z = fmaxf(acc[i][2] + bb.z, 0.f);
        o.w = fmaxf(acc[i][3] + bb.w, 0.f);
        *(float4*)(hbuf + (size_t)(r0 + i)*HIDDEN + j0) = o;
    }
}

/* ---------------- K5: logits = h @ W2 + b2  (fp32 SGEMM) --------------
   BM=128 BN=64 BK=16, 256 thr, 8x4 per thread. Swizzled block order:
   groups of 8 n-blocks x 16 m-blocks share W2/h panels in L2.          */
#define BM 128
#define BN 64
#define BK 16
__global__ __launch_bounds__(256) void k_lmhead(const float* __restrict__ hbuf,
                                                const float* __restrict__ W2,
                                                const float* __restrict__ b2,
                                                float* __restrict__ logits) {
    __shared__ float As[BK][BM];               /* 8 KB */
    __shared__ float Bs[BK][BN];               /* 4 KB */
    int bid = blockIdx.x;
    int g = bid >> 7, i = bid & 127;
    int bn = g*8 + (i >> 4);
    int bm = i & 15;
    int tid = threadIdx.x;
    int tx = tid & 15, ty = tid >> 4;          /* tx: n-dir(4), ty: m-dir(8) */
    int r0 = bm * BM, v0 = bn * BN;

    int am  = tid >> 1;                        /* 0..127 */
    int ak0 = (tid & 1) * 8;
    int bkk = tid >> 4;                        /* 0..15  */
    int bn0 = (tid & 15) * 4;

    float acc[8][4];
#pragma unroll
    for (int a = 0; a < 8; a++)
#pragma unroll
        for (int c = 0; c < 4; c++) acc[a][c] = 0.f;

    for (int k0 = 0; k0 < HIDDEN; k0 += BK) {
        /* stage A (transposed) */
        float4 a0 = *(const float4*)(hbuf + (size_t)(r0 + am)*HIDDEN + k0 + ak0);
        float4 a1 = *(const float4*)(hbuf + (size_t)(r0 + am)*HIDDEN + k0 + ak0 + 4);
        As[ak0+0][am] = a0.x; As[ak0+1][am] = a0.y; As[ak0+2][am] = a0.z; As[ak0+3][am] = a0.w;
        As[ak0+4][am] = a1.x; As[ak0+5][am] = a1.y; As[ak0+6][am] = a1.z; As[ak0+7][am] = a1.w;
        /* stage B (guarded, W2 rows are odd-stride -> scalar loads) */
        const float* wrow = W2 + (size_t)(k0 + bkk)*VOCAB;
        int col = v0 + bn0;
        float b0_ = (col+0 < VOCAB) ? wrow[col+0] : 0.f;
        float b1_ = (col+1 < VOCAB) ? wrow[col+1] : 0.f;
        float b2_ = (col+2 < VOCAB) ? wrow[col+2] : 0.f;
        float b3_ = (col+3 < VOCAB) ? wrow[col+3] : 0.f;
        *(float4*)&Bs[bkk][bn0] = make_float4(b0_, b1_, b2_, b3_);
        __syncthreads();
#pragma unroll
        for (int kk = 0; kk < BK; kk++) {
            float a[8], bq[4];
            *(float4*)&a[0] = *(const float4*)&As[kk][ty*8];
            *(float4*)&a[4] = *(const float4*)&As[kk][ty*8 + 4];
            *(float4*)&bq[0] = *(const float4*)&Bs[kk][tx*4];
#pragma unroll
            for (int ii = 0; ii < 8; ii++)
#pragma unroll
                for (int jj = 0; jj < 4; jj++) acc[ii][jj] += a[ii] * bq[jj];
        }
        __syncthreads();
    }
    float bv[4];
#pragma unroll
    for (int jj = 0; jj < 4; jj++) {
        int vv = v0 + tx*4 + jj;
        bv[jj] = (vv < VOCAB) ? b2[vv] : 0.f;
    }
#pragma unroll
    for (int ii = 0; ii < 8; ii++) {
        int m = r0 + ty*8 + ii;
        float* row = logits + (size_t)m * VOCAB;
#pragma unroll
        for (int jj = 0; jj < 4; jj++) {
            int vv = v0 + tx*4 + jj;
            if (vv < VOCAB) row[vv] = acc[ii][jj] + bv[jj];
        }
    }
}

/* -------- K6: per-row online logsumexp + per-row NLL ------------------ */
__global__ void k_rowstats(const float* __restrict__ logits, const int* __restrict__ tgt,
                           float* __restrict__ rowM, float* __restrict__ rowRL,
                           float* __restrict__ nll) {
    __shared__ float sm[256], sl[256];
    int r = blockIdx.x, tid = threadIdx.x;
    const float* row = logits + (size_t)r * VOCAB;
    float m = -1e30f, l = 0.f;
    for (int i = tid; i < VOCAB; i += 256) {
        float xv = row[i];
        float nm = fmaxf(m, xv);
        l = l * __expf(m - nm) + __expf(xv - nm);
        m = nm;
    }
    sm[tid] = m; sl[tid] = l;
    __syncthreads();
    for (int off = 128; off > 0; off >>= 1) {
        if (tid < off) {
            float m2 = sm[tid + off], l2 = sl[tid + off];
            float nm = fmaxf(sm[tid], m2);
            sl[tid] = sl[tid] * __expf(sm[tid] - nm) + l2 * __expf(m2 - nm);
            sm[tid] = nm;
        }
        __syncthreads();
    }
    if (tid == 0) {
        float M = sm[0], L = sl[0];
        rowM[r] = M;
        rowRL[r] = 1.0f / L;
        nll[r] = (M + logf(L)) - row[tgt[r]];
    }
}

/* -------- K7: loss = mean(nll) ---------------------------------------- */
__global__ void k_loss(const float* __restrict__ nll, float* __restrict__ out_loss) {
    __shared__ float s[256];
    int tid = threadIdx.x;
    float a = 0.f;
    for (int i = tid; i < ROWS; i += 256) a += nll[i];
    s[tid] = a;
    __syncthreads();
    for (int off = 128; off > 0; off >>= 1) {
        if (tid < off) s[tid] += s[tid + off];
        __syncthreads();
    }
    if (tid == 0) out_loss[0] = s[0] / (float)ROWS;
}

/* -------- K8: o_prob = exp(logits - M) * RL --------------------------- */
__global__ void k_probs(const float* __restrict__ logits, const float* __restrict__ rowM,
                        const float* __restrict__ rowRL, float* __restrict__ oprob) {
    int r = blockIdx.x, tid = threadIdx.x;
    size_t base = (size_t)r * VOCAB;
    float M = rowM[r], RL = rowRL[r];
    int head = (4 - (r & 3)) & 3;
    for (int i = tid; i < head; i += 256)
        oprob[base + i] = __expf(logits[base + i] - M) * RL;
    int nvec = (VOCAB - head) >> 2;
    const float4* in4 = (const float4*)(logits + base + head);
    float4* out4 = (float4*)(oprob + base + head);
    for (int i = tid; i < nvec; i += 256) {
        float4 xv = in4[i];
        float4 o;
        o.x = __expf(xv.x - M) * RL;
        o.y = __expf(xv.y - M) * RL;
        o.z = __expf(xv.z - M) * RL;
        o.w = __expf(xv.w - M) * RL;
        out4[i] = o;
    }
    for (int i = head + nvec*4 + tid; i < VOCAB; i += 256)
        oprob[base + i] = __expf(logits[base + i] - M) * RL;
}

extern "C" void kernel_launch(void* const* d_in, const int* in_sizes, int n_in,
                              void* d_out, int out_size, void* d_ws, size_t ws_size,
                              hipStream_t stream) {
    const int*   idx = (const int*)d_in[0];
    const int*   tgt = (const int*)d_in[1];
    const float* tok = (const float*)d_in[2];
    const float* pos = (const float*)d_in[3];
    const float* Wq  = (const float*)d_in[4];
    const float* Wk  = (const float*)d_in[5];
    const float* Wv  = (const float*)d_in[6];
    const float* W1  = (const float*)d_in[7];
    const float* b1  = (const float*)d_in[8];
    const float* W2  = (const float*)d_in[9];
    const float* b2  = (const float*)d_in[10];

    float* logits = (float*)d_out;
    float* loss   = logits + LOGN;
    float* oprob  = logits + LOGN + 1;

    /* workspace layout (floats), total ~4.76M floats = ~19 MB */
    float* ws    = (float*)d_ws;
    float* x     = ws;                     /* 524288  */
    float* q     = x     + 524288;         /* 524288  */
    float* k     = q     + 524288;
    float* v     = k     + 524288;
    float* colM  = v     + 524288;         /* 16384   */
    float* colRL = colM  + 16384;          /* 16384   */
    float* att   = colRL + 16384;          /* 524288  */
    float* hbuf  = att   + 524288;         /* 2097152 */
    float* rowM  = hbuf  + 2097152;        /* 2048    */
    float* rowRL = rowM  + 2048;           /* 2048    */
    float* nll   = rowRL + 2048;           /* 2048    */

    k_embed   <<<ROWS, EMBED, 0, stream>>>(idx, tok, pos, x);
    k_qkv     <<<ROWS, 256,   0, stream>>>(x, Wq, Wk, Wv, q, k, v);
    k_colstats<<<NHEAD*BATCH, TLEN, 0, stream>>>(q, k, colM, colRL);
    k_attnout <<<NHEAD*BATCH, TLEN, 0, stream>>>(q, k, v, colM, colRL, att);
    k_mlp     <<<ROWS/8, 256, 0, stream>>>(att, W1, b1, hbuf);
    /* 16 m-blocks x ceil(50257/64)=786 n-blocks = 12576 blocks */
    k_lmhead  <<<12576, 256, 0, stream>>>(hbuf, W2, b2, logits);
    k_rowstats<<<ROWS, 256, 0, stream>>>(logits, tgt, rowM, rowRL, nll);
    k_loss    <<<1, 256, 0, stream>>>(nll, loss);
    k_probs   <<<ROWS, 256, 0, stream>>>(logits, rowM, rowRL, oprob);
}